// Round 19
// baseline (158.973 us; speedup 1.0000x reference)
//
#include <hip/hip_runtime.h>
#include <hip/hip_bf16.h>

typedef short short8 __attribute__((ext_vector_type(8)));
typedef float f32x4 __attribute__((ext_vector_type(4)));
typedef float f32x16 __attribute__((ext_vector_type(16)));

#define HDIM 1024
#define TSEQ 2048
#define BATCH 4
#define NH 16
#define HD 64
#define SCALE_Q 0.18033688011f   // 0.125 * log2(e)
#define BHT (BATCH * NH * TSEQ)  // 131072 rows

__device__ __forceinline__ unsigned short f2bf(float f) {
  union { float f; unsigned u; } x; x.f = f;
  unsigned r = x.u + 0x7fffu + ((x.u >> 16) & 1u);
  return (unsigned short)(r >> 16);
}

__device__ __forceinline__ float bf2f(unsigned short u) {
  union { unsigned u; float f; } z; z.u = (unsigned)u << 16; return z.f;
}

__device__ __forceinline__ unsigned pk2(float a, float b) {
  __hip_bfloat162 h2 = __float22bfloat162_rn(float2{a, b});
  union { __hip_bfloat162 h; unsigned u; } u2; u2.h = h2;
  return u2.u;
}

// 16B-slot XOR swizzle within a 128B row (8 slots)
__device__ __forceinline__ int swz(int row, int slot) { return slot ^ (row & 7); }

// async global->LDS DMA, 16B per lane; LDS dest = uniform base + lane*16
typedef const __attribute__((address_space(1))) void* gas_ptr;
typedef __attribute__((address_space(3))) void* las_ptr;
__device__ __forceinline__ void gl2lds16(const void* g, void* l) {
  __builtin_amdgcn_global_load_lds((gas_ptr)g, (las_ptr)l, 16, 0, 0);
}

// exchange: x' = [own x (lanes<32) | partner y], y' = [partner x | own y (lanes>=32)]
__device__ __forceinline__ void pswap(unsigned& x, unsigned& y) {
#if __has_builtin(__builtin_amdgcn_permlane32_swap)
  typedef int i32x2 __attribute__((ext_vector_type(2)));
  i32x2 r = __builtin_amdgcn_permlane32_swap((int)x, (int)y, false, false);
  x = (unsigned)r[0]; y = (unsigned)r[1];
#else
  unsigned px = (unsigned)__shfl_xor((int)x, 32);
  unsigned py = (unsigned)__shfl_xor((int)y, 32);
  bool hiHalf = (threadIdx.x & 32) != 0;
  unsigned nx = hiHalf ? py : x;
  unsigned ny = hiHalf ? y : px;
  x = nx; y = ny;
#endif
}

// ---------------- fused prep: LN (blocks 0..8191) + weight convert (8192..12287)
//                  + mask compaction (12288..12291) ----------------
__global__ __launch_bounds__(256) void prep_kernel(
    const float* __restrict__ x, const float* __restrict__ g,
    const float* __restrict__ bta, unsigned short* __restrict__ h,
    const float* __restrict__ wq, const float* __restrict__ wk,
    const float* __restrict__ wv, const float* __restrict__ wo,
    unsigned short* __restrict__ wout,
    const int* __restrict__ mask, int* __restrict__ idx,
    float* __restrict__ bias, int* __restrict__ meta) {
  const int bid = blockIdx.x, tid = threadIdx.x;
  __shared__ float red[8];
  __shared__ int wsum[4];
  if (bid < 8192) {
    // ---- LayerNorm row -> bf16 ----
    const int row = bid;
    const float* xr = x + (size_t)row * HDIM;
    float4 v = *reinterpret_cast<const float4*>(xr + tid * 4);
    float s = v.x + v.y + v.z + v.w;
    float sq = v.x * v.x + v.y * v.y + v.z * v.z + v.w * v.w;
    for (int m = 32; m; m >>= 1) { s += __shfl_xor(s, m); sq += __shfl_xor(sq, m); }
    int w = tid >> 6, l = tid & 63;
    if (l == 0) { red[w] = s; red[4 + w] = sq; }
    __syncthreads();
    s = red[0] + red[1] + red[2] + red[3];
    sq = red[4] + red[5] + red[6] + red[7];
    float mu = s * (1.0f / HDIM);
    float var = sq * (1.0f / HDIM) - mu * mu;
    float inv = rsqrtf(var + 1e-5f);
    float4 gv = *reinterpret_cast<const float4*>(g + tid * 4);
    float4 bv = *reinterpret_cast<const float4*>(bta + tid * 4);
    unsigned short o0 = f2bf((v.x - mu) * inv * gv.x + bv.x);
    unsigned short o1 = f2bf((v.y - mu) * inv * gv.y + bv.y);
    unsigned short o2 = f2bf((v.z - mu) * inv * gv.z + bv.z);
    unsigned short o3 = f2bf((v.w - mu) * inv * gv.w + bv.w);
    uint2 o; o.x = (unsigned)o0 | ((unsigned)o1 << 16); o.y = (unsigned)o2 | ((unsigned)o3 << 16);
    *reinterpret_cast<uint2*>(h + (size_t)row * HDIM + tid * 4) = o;
  } else if (bid < 8192 + 4096) {
    // ---- weight fp32 -> bf16, 4 elems/thread ----
    size_t i = ((size_t)(bid - 8192) * 256 + tid) * 4;
    int which = (int)(i >> 20);                 // H*H = 2^20
    const float* src = which == 0 ? wq : which == 1 ? wk : which == 2 ? wv : wo;
    size_t off = i & ((1u << 20) - 1);
    float4 v = *reinterpret_cast<const float4*>(src + off);
    unsigned lo = (unsigned)f2bf(v.x) | ((unsigned)f2bf(v.y) << 16);
    unsigned hi = (unsigned)f2bf(v.z) | ((unsigned)f2bf(v.w) << 16);
    uint2 o; o.x = lo; o.y = hi;
    *reinterpret_cast<uint2*>(wout + i) = o;
  } else {
    // ---- key compaction for batch b: idx of unmasked keys + pad bias ----
    const int b = bid - (8192 + 4096);
    const int l = tid & 63, w = tid >> 6;
    const int* mp = mask + b * TSEQ;
    const int base = tid * 8;
    int keep[8]; int cnt = 0;
#pragma unroll
    for (int j = 0; j < 8; ++j) { keep[j] = (mp[base + j] == 0); cnt += keep[j]; }
    int inc = cnt;
    for (int s = 1; s < 64; s <<= 1) {
      int t = __shfl_up(inc, s);
      if (l >= s) inc += t;
    }
    if (l == 63) wsum[w] = inc;
    __syncthreads();
    int wbase = 0;
#pragma unroll
    for (int i = 0; i < 4; ++i) if (i < w) wbase += wsum[i];
    const int total = wsum[0] + wsum[1] + wsum[2] + wsum[3];
    int pos = wbase + inc - cnt;   // exclusive prefix
#pragma unroll
    for (int j = 0; j < 8; ++j)
      if (keep[j]) idx[b * TSEQ + (pos++)] = base + j;
    for (int i = tid; i < TSEQ; i += 256) {
      if (i >= total) idx[b * TSEQ + i] = 0;
      bias[b * TSEQ + i] = (i < total) ? -16.0f : -1e30f;
    }
    if (tid == 0) {
      int cntp = (total + 63) & ~63;
      if (cntp == 0) cntp = 64;
      meta[b * 2 + 0] = cntp;        // padded key count
      meta[b * 2 + 1] = cntp >> 6;   // tiles of 64
    }
  }
}

// ---------------- GEMM: C = A(bf16 MxK) * W^T(bf16 NxK) + bias ----------------
// 512 threads / 8 waves; 128x128 tile; wave sub-tile 64x32 (acc[4][2]).
// Single-buffered LDS, non-persistent grid (R12-proven best).
// Decode: xcd=flat&7, bm=(g&7)*8+xcd (strided panels), bn=g>>3.
// MODE 0: merged QKV, N=3072 (Wb rows = q|k|v). z=bn>>3 block-uniform.
// MODE 1: out-proj (N=1024) -> fp32 out = acc + bias + xres
template <int MODE>
__global__ __launch_bounds__(512) void gemm_k(
    const unsigned short* __restrict__ A, const unsigned short* __restrict__ Wb,
    const float* __restrict__ b0, const float* __restrict__ b1, const float* __restrict__ b2,
    unsigned short* __restrict__ o0, unsigned short* __restrict__ o1, unsigned short* __restrict__ o2,
    const float* __restrict__ xres, float* __restrict__ outf,
    const int* __restrict__ idxp, const int* __restrict__ metap) {
  __shared__ __align__(16) unsigned short Alds[128 * 64];
  __shared__ __align__(16) unsigned short Wlds[128 * 64];
  const int flat = blockIdx.x;
  const int xcd = flat & 7, g = flat >> 3;
  const int bm = (g & 7) * 8 + xcd;      // strided panels per XCD
  const int bn = g >> 3;                 // MODE0: 0..23, MODE1: 0..7
  const int z = (MODE == 0) ? (bn >> 3) : 0;
  if (MODE == 0 && z != 0) {   // skip fully-padded K/V blocks (block-uniform)
    int bb = bm >> 4, t0 = (bm & 15) * 128;
    if (t0 >= metap[bb * 2]) return;
  }
  const float* bias = (z == 0) ? b0 : (z == 1) ? b1 : b2;
  unsigned short* obf = (z == 0) ? o0 : (z == 1) ? o1 : o2;
  const int tid = threadIdx.x;
  const int l = tid & 63, w = tid >> 6;        // w = 0..7
  const int wr = (w >> 2) * 64, wc = (w & 3) * 32;
  const int lrow = l & 15, lk = l >> 4;
  const int sr = l >> 3;                       // lane's row-in-8 for DMA
  const int sslot = (l & 7) ^ (sr & 7);        // pre-swizzled source slot
  int agrow[2];
#pragma unroll
  for (int p = 0; p < 2; ++p) {
    int grow = bm * 128 + w * 16 + p * 8 + sr;
    if (MODE == 0 && z != 0) {
      int bb = grow >> 11;
      agrow[p] = bb * TSEQ + idxp[grow];
    } else agrow[p] = grow;
  }
  f32x4 acc[4][2] = {};
  for (int kt = 0; kt < 16; ++kt) {
    __syncthreads();
#pragma unroll
    for (int p = 0; p < 2; ++p) {
      int rb = w * 16 + p * 8;                 // uniform per wave
      gl2lds16(A + (size_t)agrow[p] * HDIM + kt * 64 + sslot * 8, Alds + rb * 64);
      gl2lds16(Wb + (size_t)(bn * 128 + rb + sr) * HDIM + kt * 64 + sslot * 8, Wlds + rb * 64);
    }
    __syncthreads();
#pragma unroll
    for (int ks = 0; ks < 2; ++ks) {
      short8 af[4], bfr[2];
#pragma unroll
      for (int rt = 0; rt < 4; ++rt) {
        int row = wr + rt * 16 + lrow;
        af[rt] = *reinterpret_cast<const short8*>(reinterpret_cast<char*>(Alds) + row * 128 + swz(row, ks * 4 + lk) * 16);
      }
#pragma unroll
      for (int ct = 0; ct < 2; ++ct) {
        int row = wc + ct * 16 + lrow;
        bfr[ct] = *reinterpret_cast<const short8*>(reinterpret_cast<char*>(Wlds) + row * 128 + swz(row, ks * 4 + lk) * 16);
      }
      __builtin_amdgcn_s_setprio(1);           // T5: favor MFMA-entering waves
#pragma unroll
      for (int rt = 0; rt < 4; ++rt)
#pragma unroll
        for (int ct = 0; ct < 2; ++ct)
          acc[rt][ct] = __builtin_amdgcn_mfma_f32_16x16x32_bf16(af[rt], bfr[ct], acc[rt][ct], 0, 0, 0);
      __builtin_amdgcn_s_setprio(0);
    }
  }
#pragma unroll
  for (int rt = 0; rt < 4; ++rt) {
#pragma unroll
    for (int ct = 0; ct < 2; ++ct) {
      int ncol = bn * 128 + wc + ct * 16 + lrow;   // MODE0: 0..3071
      int col = ncol & (HDIM - 1);
      float bv = bias[col];
      if (MODE == 0 && z == 2) {
        int mrow0 = bm * 128 + wr + rt * 16 + lk * 4;
        int bb = mrow0 >> 11, t0 = mrow0 & (TSEQ - 1);
        int head = (col >> 6) & 15, d = col & 63;
        uint2 pw;
        pw.x = pk2(acc[rt][ct][0] + bv, acc[rt][ct][1] + bv);
        pw.y = pk2(acc[rt][ct][2] + bv, acc[rt][ct][3] + bv);
        *reinterpret_cast<uint2*>(obf + ((size_t)(bb * NH + head) * HD + d) * TSEQ + t0) = pw;
      } else {
#pragma unroll
        for (int r = 0; r < 4; ++r) {
          int mrow = bm * 128 + wr + rt * 16 + lk * 4 + r;
          float val = acc[rt][ct][r] + bv;
          if (MODE == 0) {
            if (z == 0) val *= SCALE_Q;       // fold 1/sqrt(HEAD) * log2(e) into Q
            int bb = mrow >> 11, t = mrow & (TSEQ - 1);
            int head = (col >> 6) & 15, d = col & 63;
            obf[((size_t)(bb * NH + head) * TSEQ + t) * HD + d] = f2bf(val);
          } else {
            size_t idx = (size_t)mrow * HDIM + col;
            outf[idx] = val + xres[idx];
          }
        }
      }
    }
  }
}

// ---------------- flash attention: 32x32 MFMA, fixed-shift softmax, KV-split-2 --
// grid: 1024 blocks = 2 splits x (8 qb x 64 bh XCD-swizzled); block 512 (8 waves).
// Fixed softmax shift: bias = -16 valid / -1e30 pad folded into MFMA C-init;
// no online max, no rescale; partials (acc bf16, lsum f32) summed by combine_k.
__global__ __launch_bounds__(512) void attn_kernel(
    const unsigned short* __restrict__ q_s, const unsigned short* __restrict__ k_s,
    const unsigned short* __restrict__ vt_s, const float* __restrict__ mzf,
    const int* __restrict__ meta, float* __restrict__ pl,
    unsigned short* __restrict__ pa) {
  __shared__ __align__(16) unsigned short Klds[2][64 * 64];  // 16KB dbuf (rows k)
  __shared__ __align__(16) unsigned short Vlds[2][64 * 64];  // 16KB dbuf (rows d)
  const int flat = blockIdx.x & 511;
  const int split = blockIdx.x >> 9;
  const int qb = (flat >> 3) & 7;
  const int hb = ((flat >> 6) << 3) | (flat & 7);   // head + 16*b
  const int head = hb & 15, b = hb >> 4;
  const int ntiles = meta[b * 2 + 1];
  const int nt0 = (ntiles + 1) >> 1;
  const int tb = split ? nt0 : 0;
  const int te = split ? ntiles : nt0;
  const unsigned short* qp = q_s + ((size_t)(b * NH + head) * TSEQ + qb * 256) * HD;
  const unsigned short* kp = k_s + (size_t)(b * NH + head) * TSEQ * HD;
  const unsigned short* vtp = vt_s + (size_t)(b * NH + head) * HD * TSEQ;
  const float* mp = mzf + b * TSEQ;
  const int tid = threadIdx.x, l = tid & 63, w = tid >> 6;   // w = 0..7
  const int ln = l & 31, h = l >> 5;
  const int sr = l >> 3;                       // DMA: lane's row-in-8
  const int sslot = (l & 7) ^ (sr & 7);        // pre-swizzled source slot

  // Q frags (B-operand 32x32x16): lane holds Q[q = w*32 + ln][d = dk*16 + h*8 ..+7]
  short8 qf[4];
  {
    const unsigned short* qrp = qp + (size_t)(w * 32 + ln) * HD;
#pragma unroll
    for (int dk = 0; dk < 4; ++dk)
      qf[dk] = *reinterpret_cast<const short8*>(qrp + dk * 16 + h * 8);
  }

  f32x16 acc0 = {}, acc1 = {};
  float lsum = 0.0f;   // per-lane (own k-half) partial

  auto KSTAGE = [&](int kv2, int bi2) {
    int rb = w * 8;                            // each wave stages 8 rows
    gl2lds16(kp + (size_t)(kv2 * 64 + rb + sr) * HD + sslot * 8, &Klds[bi2][rb * 64]);
  };
  auto VSTAGE = [&](int kv2, int bi2) {
    int rb = w * 8;
    gl2lds16(vtp + (size_t)(rb + sr) * TSEQ + kv2 * 64 + sslot * 8, &Vlds[bi2][rb * 64]);
  };

  if (tb < te) { KSTAGE(tb, 0); VSTAGE(tb, 0); }

  for (int kv = tb; kv < te; ++kv) {
    const int bi = (kv - tb) & 1;
    const char* Kb = reinterpret_cast<const char*>(&Klds[bi][0]);
    const char* Vb = reinterpret_cast<const char*>(&Vlds[bi][0]);
    __syncthreads();   // drains own DMA (tile kv landed); buf[bi^1] free
    if (kv + 1 < te) { KSTAGE(kv + 1, bi ^ 1); VSTAGE(kv + 1, bi ^ 1); }

    // ---- C-init: -16 (fixed shift) for interior tiles; bias array on last ----
    f32x16 st0, st1;
    if (kv == ntiles - 1) {
#pragma unroll
      for (int kt2 = 0; kt2 < 2; ++kt2) {
        f32x16& s = kt2 ? st1 : st0;
#pragma unroll
        for (int gg = 0; gg < 4; ++gg) {
          f32x4 m4 = *reinterpret_cast<const f32x4*>(mp + kv * 64 + kt2 * 32 + gg * 8 + 4 * h);
#pragma unroll
          for (int t = 0; t < 4; ++t) s[gg * 4 + t] = m4[t];
        }
      }
    } else {
#pragma unroll
      for (int r = 0; r < 16; ++r) { st0[r] = -16.0f; st1[r] = -16.0f; }
    }

    // ---- S^T = K Q^T + C. st rows k = kt2*32 + crow(r,h), col q = ln ----
    __builtin_amdgcn_s_setprio(1);
#pragma unroll
    for (int kt2 = 0; kt2 < 2; ++kt2) {
      f32x16& s = kt2 ? st1 : st0;
      int row = kt2 * 32 + ln;
#pragma unroll
      for (int dk = 0; dk < 4; ++dk) {
        int slot = (dk * 2 + h) ^ (row & 7);
        short8 kf = *reinterpret_cast<const short8*>(Kb + row * 128 + slot * 16);
        s = __builtin_amdgcn_mfma_f32_32x32x16_bf16(kf, qf[dk], s, 0, 0, 0);
      }
    }
    __builtin_amdgcn_s_setprio(0);

    // ---- P = exp2(S) directly (shift already in C-init); accumulate lsum ----
#pragma unroll
    for (int r = 0; r < 16; ++r) {
      st0[r] = __builtin_amdgcn_exp2f(st0[r]);
      st1[r] = __builtin_amdgcn_exp2f(st1[r]);
    }
    {
      f32x16 sv = st0 + st1;
      float s0 = (sv[0] + sv[1]) + (sv[2] + sv[3]);
      float s1 = (sv[4] + sv[5]) + (sv[6] + sv[7]);
      float s2 = (sv[8] + sv[9]) + (sv[10] + sv[11]);
      float s3 = (sv[12] + sv[13]) + (sv[14] + sv[15]);
      lsum += (s0 + s1) + (s2 + s3);
    }

    // ---- PV: build P A-frags in-register (cvt_pk + permlane), V from LDS ----
    __builtin_amdgcn_s_setprio(1);
#pragma unroll
    for (int ks = 0; ks < 4; ++ks) {
      const f32x16& p2 = (ks >> 1) ? st1 : st0;
      const int a = 8 * (ks & 1);
      unsigned X0 = pk2(p2[a + 0], p2[a + 1]);
      unsigned X1 = pk2(p2[a + 2], p2[a + 3]);
      unsigned Y0 = pk2(p2[a + 4], p2[a + 5]);
      unsigned Y1 = pk2(p2[a + 6], p2[a + 7]);
      pswap(X0, Y0);   // X0 -> words j0j1, Y0 -> words j4j5
      pswap(X1, Y1);   // X1 -> j2j3, Y1 -> j6j7
      union { unsigned u[4]; short8 s; } pf;
      pf.u[0] = X0; pf.u[1] = X1; pf.u[2] = Y0; pf.u[3] = Y1;
#pragma unroll
      for (int dc = 0; dc < 2; ++dc) {
        int row = dc * 32 + ln;
        int slot = (ks * 2 + h) ^ (row & 7);
        short8 vf = *reinterpret_cast<const short8*>(Vb + row * 128 + slot * 16);
        if (dc == 0)
          acc0 = __builtin_amdgcn_mfma_f32_32x32x16_bf16(pf.s, vf, acc0, 0, 0, 0);
        else
          acc1 = __builtin_amdgcn_mfma_f32_32x32x16_bf16(pf.s, vf, acc1, 0, 0, 0);
      }
    }
    __builtin_amdgcn_s_setprio(0);
  }

  // ---- epilogue: write UNNORMALIZED partials (combine_k divides) ----
  lsum += __shfl_xor(lsum, 32);
  const size_t rowbase = (size_t)(b * NH + head) * TSEQ + qb * 256 + w * 32;
  if (l < 32) pl[(size_t)split * BHT + rowbase + l] = lsum;
  unsigned short* pap = pa + (size_t)split * BHT * HD + rowbase * HD;
#pragma unroll
  for (int r = 0; r < 16; ++r) {
    int cr = (r & 3) + 8 * (r >> 2) + 4 * h;
    pap[cr * HD + ln] = f2bf(acc0[r]);
    pap[cr * HD + 32 + ln] = f2bf(acc1[r]);
  }
}

// ---------------- combine: c = (pa0 + pa1) / (l0 + l1), scatter to (B,T,H) ----
__global__ __launch_bounds__(256) void combine_k(
    const unsigned short* __restrict__ pa, const float* __restrict__ pl,
    unsigned short* __restrict__ c) {
  int gid = blockIdx.x * 256 + threadIdx.x;      // 0 .. BHT*HD/8-1
  int row = gid >> 3;                             // bh*TSEQ + t
  int d0 = (gid & 7) << 3;
  float inv = 1.0f / (pl[row] + pl[BHT + row]);
  const unsigned short* a0 = pa + (size_t)row * HD + d0;
  const unsigned short* a1 = a0 + (size_t)BHT * HD;
  short8 v0 = *reinterpret_cast<const short8*>(a0);
  short8 v1 = *reinterpret_cast<const short8*>(a1);
  union { unsigned short u[8]; short8 s; } o;
#pragma unroll
  for (int j = 0; j < 8; ++j)
    o.u[j] = f2bf((bf2f((unsigned short)v0[j]) + bf2f((unsigned short)v1[j])) * inv);
  int bh = row >> 11, t = row & (TSEQ - 1);
  int b = bh >> 4, head = bh & 15;
  *reinterpret_cast<short8*>(c + ((size_t)(b * TSEQ + t)) * HDIM + head * HD + d0) = o.s;
}

extern "C" void kernel_launch(void* const* d_in, const int* in_sizes, int n_in,
                              void* d_out, int out_size, void* d_ws, size_t ws_size,
                              hipStream_t stream) {
  const float* x   = (const float*)d_in[0];
  const int* mask  = (const int*)d_in[1];
  const float* lng = (const float*)d_in[2];
  const float* lnb = (const float*)d_in[3];
  const float* wq  = (const float*)d_in[4];
  const float* bq  = (const float*)d_in[5];
  const float* wk  = (const float*)d_in[6];
  const float* bk  = (const float*)d_in[7];
  const float* wv  = (const float*)d_in[8];
  const float* bv  = (const float*)d_in[9];
  const float* wo  = (const float*)d_in[10];
  const float* bo  = (const float*)d_in[11];
  float* out = (float*)d_out;
  char* ws = (char*)d_ws;

  unsigned short* h   = (unsigned short*)ws;                       // 16MB (B*T*H bf16)
  unsigned short* wbf = (unsigned short*)(ws + (16u << 20));       // 8MB (4 weights bf16)
  unsigned short* qs  = (unsigned short*)(ws + (24u << 20));       // 16MB
  unsigned short* ksb = (unsigned short*)(ws + (40u << 20));       // 16MB (compacted K)
  unsigned short* vt  = (unsigned short*)(ws + (56u << 20));       // 16MB (compacted V^T)
  float*          mzf = (float*)(ws + (72u << 20));                // 32KB pad bias
  int*            idx = (int*)(ws + (72u << 20) + (64u << 10));    // 32KB gather idx
  int*            met = (int*)(ws + (72u << 20) + (128u << 10));   // meta
  unsigned short* pa  = (unsigned short*)(ws + (76u << 20));       // 2x16MB partial O
  float*          pl  = (float*)(ws + (108u << 20));               // 2x512KB partial lsum
  unsigned short* c   = h;  // h dead after QKV GEMM

  prep_kernel<<<dim3(8192 + 4096 + BATCH), 256, 0, stream>>>(
      x, lng, lnb, h, wq, wk, wv, wo, wbf, mask, idx, mzf, met);
  gemm_k<0><<<dim3(1536), 512, 0, stream>>>(h, wbf, bq, bk, bv, qs, ksb, vt,
                                            nullptr, nullptr, idx, met);
  attn_kernel<<<dim3(1024), dim3(512), 0, stream>>>(qs, ksb, vt, mzf, met, pl, pa);
  combine_k<<<dim3(BHT * HD / 8 / 256), 256, 0, stream>>>(pa, pl, c);
  gemm_k<1><<<dim3(512), 512, 0, stream>>>(c, wbf + (size_t)3 * HDIM * HDIM, bo, nullptr, nullptr,
                                           nullptr, nullptr, nullptr, x, out, nullptr, nullptr);
}

// Round 20
// 152.547 us; speedup vs baseline: 1.0421x; 1.0421x over previous
//
#include <hip/hip_runtime.h>
#include <hip/hip_bf16.h>

typedef short short8 __attribute__((ext_vector_type(8)));
typedef float f32x4 __attribute__((ext_vector_type(4)));
typedef float f32x16 __attribute__((ext_vector_type(16)));

#define HDIM 1024
#define TSEQ 2048
#define BATCH 4
#define NH 16
#define HD 64
#define SCALE_Q 0.18033688011f   // 0.125 * log2(e)
#define BHT (BATCH * NH * TSEQ)  // 131072 rows

__device__ __forceinline__ unsigned short f2bf(float f) {
  union { float f; unsigned u; } x; x.f = f;
  unsigned r = x.u + 0x7fffu + ((x.u >> 16) & 1u);
  return (unsigned short)(r >> 16);
}

__device__ __forceinline__ float bf2f(unsigned short u) {
  union { unsigned u; float f; } z; z.u = (unsigned)u << 16; return z.f;
}

__device__ __forceinline__ unsigned pk2(float a, float b) {
  __hip_bfloat162 h2 = __float22bfloat162_rn(float2{a, b});
  union { __hip_bfloat162 h; unsigned u; } u2; u2.h = h2;
  return u2.u;
}

// 16B-slot XOR swizzle within a 128B row (8 slots)
__device__ __forceinline__ int swz(int row, int slot) { return slot ^ (row & 7); }

// async global->LDS DMA, 16B per lane; LDS dest = uniform base + lane*16
typedef const __attribute__((address_space(1))) void* gas_ptr;
typedef __attribute__((address_space(3))) void* las_ptr;
__device__ __forceinline__ void gl2lds16(const void* g, void* l) {
  __builtin_amdgcn_global_load_lds((gas_ptr)g, (las_ptr)l, 16, 0, 0);
}

// exchange: x' = [own x (lanes<32) | partner y], y' = [partner x | own y (lanes>=32)]
__device__ __forceinline__ void pswap(unsigned& x, unsigned& y) {
#if __has_builtin(__builtin_amdgcn_permlane32_swap)
  typedef int i32x2 __attribute__((ext_vector_type(2)));
  i32x2 r = __builtin_amdgcn_permlane32_swap((int)x, (int)y, false, false);
  x = (unsigned)r[0]; y = (unsigned)r[1];
#else
  unsigned px = (unsigned)__shfl_xor((int)x, 32);
  unsigned py = (unsigned)__shfl_xor((int)y, 32);
  bool hiHalf = (threadIdx.x & 32) != 0;
  unsigned nx = hiHalf ? py : x;
  unsigned ny = hiHalf ? y : px;
  x = nx; y = ny;
#endif
}

// ---------------- fused prep: LN (blocks 0..8191) + weight convert (8192..12287)
//                  + mask compaction (12288..12291) ----------------
__global__ __launch_bounds__(256) void prep_kernel(
    const float* __restrict__ x, const float* __restrict__ g,
    const float* __restrict__ bta, unsigned short* __restrict__ h,
    const float* __restrict__ wq, const float* __restrict__ wk,
    const float* __restrict__ wv, const float* __restrict__ wo,
    unsigned short* __restrict__ wout,
    const int* __restrict__ mask, int* __restrict__ idx,
    float* __restrict__ bias, int* __restrict__ meta) {
  const int bid = blockIdx.x, tid = threadIdx.x;
  __shared__ float red[8];
  __shared__ int wsum[4];
  if (bid < 8192) {
    // ---- LayerNorm row -> bf16 ----
    const int row = bid;
    const float* xr = x + (size_t)row * HDIM;
    float4 v = *reinterpret_cast<const float4*>(xr + tid * 4);
    float s = v.x + v.y + v.z + v.w;
    float sq = v.x * v.x + v.y * v.y + v.z * v.z + v.w * v.w;
    for (int m = 32; m; m >>= 1) { s += __shfl_xor(s, m); sq += __shfl_xor(sq, m); }
    int w = tid >> 6, l = tid & 63;
    if (l == 0) { red[w] = s; red[4 + w] = sq; }
    __syncthreads();
    s = red[0] + red[1] + red[2] + red[3];
    sq = red[4] + red[5] + red[6] + red[7];
    float mu = s * (1.0f / HDIM);
    float var = sq * (1.0f / HDIM) - mu * mu;
    float inv = rsqrtf(var + 1e-5f);
    float4 gv = *reinterpret_cast<const float4*>(g + tid * 4);
    float4 bv = *reinterpret_cast<const float4*>(bta + tid * 4);
    unsigned short o0 = f2bf((v.x - mu) * inv * gv.x + bv.x);
    unsigned short o1 = f2bf((v.y - mu) * inv * gv.y + bv.y);
    unsigned short o2 = f2bf((v.z - mu) * inv * gv.z + bv.z);
    unsigned short o3 = f2bf((v.w - mu) * inv * gv.w + bv.w);
    uint2 o; o.x = (unsigned)o0 | ((unsigned)o1 << 16); o.y = (unsigned)o2 | ((unsigned)o3 << 16);
    *reinterpret_cast<uint2*>(h + (size_t)row * HDIM + tid * 4) = o;
  } else if (bid < 8192 + 4096) {
    // ---- weight fp32 -> bf16, 4 elems/thread ----
    size_t i = ((size_t)(bid - 8192) * 256 + tid) * 4;
    int which = (int)(i >> 20);                 // H*H = 2^20
    const float* src = which == 0 ? wq : which == 1 ? wk : which == 2 ? wv : wo;
    size_t off = i & ((1u << 20) - 1);
    float4 v = *reinterpret_cast<const float4*>(src + off);
    unsigned lo = (unsigned)f2bf(v.x) | ((unsigned)f2bf(v.y) << 16);
    unsigned hi = (unsigned)f2bf(v.z) | ((unsigned)f2bf(v.w) << 16);
    uint2 o; o.x = lo; o.y = hi;
    *reinterpret_cast<uint2*>(wout + i) = o;
  } else {
    // ---- key compaction for batch b: idx of unmasked keys + pad bias ----
    const int b = bid - (8192 + 4096);
    const int l = tid & 63, w = tid >> 6;
    const int* mp = mask + b * TSEQ;
    const int base = tid * 8;
    int keep[8]; int cnt = 0;
#pragma unroll
    for (int j = 0; j < 8; ++j) { keep[j] = (mp[base + j] == 0); cnt += keep[j]; }
    int inc = cnt;
    for (int s = 1; s < 64; s <<= 1) {
      int t = __shfl_up(inc, s);
      if (l >= s) inc += t;
    }
    if (l == 63) wsum[w] = inc;
    __syncthreads();
    int wbase = 0;
#pragma unroll
    for (int i = 0; i < 4; ++i) if (i < w) wbase += wsum[i];
    const int total = wsum[0] + wsum[1] + wsum[2] + wsum[3];
    int pos = wbase + inc - cnt;   // exclusive prefix
#pragma unroll
    for (int j = 0; j < 8; ++j)
      if (keep[j]) idx[b * TSEQ + (pos++)] = base + j;
    for (int i = tid; i < TSEQ; i += 256) {
      if (i >= total) idx[b * TSEQ + i] = 0;
      bias[b * TSEQ + i] = (i < total) ? -16.0f : -1e30f;
    }
    if (tid == 0) {
      int cntp = (total + 63) & ~63;
      if (cntp == 0) cntp = 64;
      meta[b * 2 + 0] = cntp;        // padded key count
      meta[b * 2 + 1] = cntp >> 6;   // tiles of 64
    }
  }
}

// ---------------- GEMM: C = A(bf16 MxK) * W^T(bf16 NxK) + bias ----------------
// 512 threads / 8 waves; 128x128 tile; wave sub-tile 64x32 (acc[4][2]).
// Single-buffered LDS, non-persistent grid (R12-proven best).
// Decode: xcd=flat&7, bm=(g&7)*8+xcd (strided panels), bn=g>>3.
// MODE 0: merged QKV, N=3072 (Wb rows = q|k|v). z=bn>>3 block-uniform.
// MODE 1: out-proj (N=1024) -> fp32 out = acc + bias + xres
template <int MODE>
__global__ __launch_bounds__(512) void gemm_k(
    const unsigned short* __restrict__ A, const unsigned short* __restrict__ Wb,
    const float* __restrict__ b0, const float* __restrict__ b1, const float* __restrict__ b2,
    unsigned short* __restrict__ o0, unsigned short* __restrict__ o1, unsigned short* __restrict__ o2,
    const float* __restrict__ xres, float* __restrict__ outf,
    const int* __restrict__ idxp, const int* __restrict__ metap) {
  __shared__ __align__(16) unsigned short Alds[128 * 64];
  __shared__ __align__(16) unsigned short Wlds[128 * 64];
  const int flat = blockIdx.x;
  const int xcd = flat & 7, g = flat >> 3;
  const int bm = (g & 7) * 8 + xcd;      // strided panels per XCD
  const int bn = g >> 3;                 // MODE0: 0..23, MODE1: 0..7
  const int z = (MODE == 0) ? (bn >> 3) : 0;
  if (MODE == 0 && z != 0) {   // skip fully-padded K/V blocks (block-uniform)
    int bb = bm >> 4, t0 = (bm & 15) * 128;
    if (t0 >= metap[bb * 2]) return;
  }
  const float* bias = (z == 0) ? b0 : (z == 1) ? b1 : b2;
  unsigned short* obf = (z == 0) ? o0 : (z == 1) ? o1 : o2;
  const int tid = threadIdx.x;
  const int l = tid & 63, w = tid >> 6;        // w = 0..7
  const int wr = (w >> 2) * 64, wc = (w & 3) * 32;
  const int lrow = l & 15, lk = l >> 4;
  const int sr = l >> 3;                       // lane's row-in-8 for DMA
  const int sslot = (l & 7) ^ (sr & 7);        // pre-swizzled source slot
  int agrow[2];
#pragma unroll
  for (int p = 0; p < 2; ++p) {
    int grow = bm * 128 + w * 16 + p * 8 + sr;
    if (MODE == 0 && z != 0) {
      int bb = grow >> 11;
      agrow[p] = bb * TSEQ + idxp[grow];
    } else agrow[p] = grow;
  }
  f32x4 acc[4][2] = {};
  for (int kt = 0; kt < 16; ++kt) {
    __syncthreads();
#pragma unroll
    for (int p = 0; p < 2; ++p) {
      int rb = w * 16 + p * 8;                 // uniform per wave
      gl2lds16(A + (size_t)agrow[p] * HDIM + kt * 64 + sslot * 8, Alds + rb * 64);
      gl2lds16(Wb + (size_t)(bn * 128 + rb + sr) * HDIM + kt * 64 + sslot * 8, Wlds + rb * 64);
    }
    __syncthreads();
#pragma unroll
    for (int ks = 0; ks < 2; ++ks) {
      short8 af[4], bfr[2];
#pragma unroll
      for (int rt = 0; rt < 4; ++rt) {
        int row = wr + rt * 16 + lrow;
        af[rt] = *reinterpret_cast<const short8*>(reinterpret_cast<char*>(Alds) + row * 128 + swz(row, ks * 4 + lk) * 16);
      }
#pragma unroll
      for (int ct = 0; ct < 2; ++ct) {
        int row = wc + ct * 16 + lrow;
        bfr[ct] = *reinterpret_cast<const short8*>(reinterpret_cast<char*>(Wlds) + row * 128 + swz(row, ks * 4 + lk) * 16);
      }
#pragma unroll
      for (int rt = 0; rt < 4; ++rt)
#pragma unroll
        for (int ct = 0; ct < 2; ++ct)
          acc[rt][ct] = __builtin_amdgcn_mfma_f32_16x16x32_bf16(af[rt], bfr[ct], acc[rt][ct], 0, 0, 0);
    }
  }
#pragma unroll
  for (int rt = 0; rt < 4; ++rt) {
#pragma unroll
    for (int ct = 0; ct < 2; ++ct) {
      int ncol = bn * 128 + wc + ct * 16 + lrow;   // MODE0: 0..3071
      int col = ncol & (HDIM - 1);
      float bv = bias[col];
      if (MODE == 0 && z == 2) {
        int mrow0 = bm * 128 + wr + rt * 16 + lk * 4;
        int bb = mrow0 >> 11, t0 = mrow0 & (TSEQ - 1);
        int head = (col >> 6) & 15, d = col & 63;
        uint2 pw;
        pw.x = pk2(acc[rt][ct][0] + bv, acc[rt][ct][1] + bv);
        pw.y = pk2(acc[rt][ct][2] + bv, acc[rt][ct][3] + bv);
        *reinterpret_cast<uint2*>(obf + ((size_t)(bb * NH + head) * HD + d) * TSEQ + t0) = pw;
      } else {
#pragma unroll
        for (int r = 0; r < 4; ++r) {
          int mrow = bm * 128 + wr + rt * 16 + lk * 4 + r;
          float val = acc[rt][ct][r] + bv;
          if (MODE == 0) {
            if (z == 0) val *= SCALE_Q;       // fold 1/sqrt(HEAD) * log2(e) into Q
            int bb = mrow >> 11, t = mrow & (TSEQ - 1);
            int head = (col >> 6) & 15, d = col & 63;
            obf[((size_t)(bb * NH + head) * TSEQ + t) * HD + d] = f2bf(val);
          } else {
            size_t idx = (size_t)mrow * HDIM + col;
            outf[idx] = val + xres[idx];
          }
        }
      }
    }
  }
}

// ---------------- flash attention: 32x32 MFMA, fixed-shift softmax, KV-split-2 --
// grid: 1024 blocks = 2 splits x (8 qb x 64 bh XCD-swizzled); block 512 (8 waves).
// Fixed softmax shift: bias = -16 valid / -1e30 pad folded into MFMA C-init;
// no online max, no rescale; partials (acc bf16, lsum f32) summed by combine_k.
__global__ __launch_bounds__(512) void attn_kernel(
    const unsigned short* __restrict__ q_s, const unsigned short* __restrict__ k_s,
    const unsigned short* __restrict__ vt_s, const float* __restrict__ mzf,
    const int* __restrict__ meta, float* __restrict__ pl,
    unsigned short* __restrict__ pa) {
  __shared__ __align__(16) unsigned short Klds[2][64 * 64];  // 16KB dbuf (rows k)
  __shared__ __align__(16) unsigned short Vlds[2][64 * 64];  // 16KB dbuf (rows d)
  const int flat = blockIdx.x & 511;
  const int split = blockIdx.x >> 9;
  const int qb = (flat >> 3) & 7;
  const int hb = ((flat >> 6) << 3) | (flat & 7);   // head + 16*b
  const int head = hb & 15, b = hb >> 4;
  const int ntiles = meta[b * 2 + 1];
  const int nt0 = (ntiles + 1) >> 1;
  const int tb = split ? nt0 : 0;
  const int te = split ? ntiles : nt0;
  const unsigned short* qp = q_s + ((size_t)(b * NH + head) * TSEQ + qb * 256) * HD;
  const unsigned short* kp = k_s + (size_t)(b * NH + head) * TSEQ * HD;
  const unsigned short* vtp = vt_s + (size_t)(b * NH + head) * HD * TSEQ;
  const float* mp = mzf + b * TSEQ;
  const int tid = threadIdx.x, l = tid & 63, w = tid >> 6;   // w = 0..7
  const int ln = l & 31, h = l >> 5;
  const int sr = l >> 3;                       // DMA: lane's row-in-8
  const int sslot = (l & 7) ^ (sr & 7);        // pre-swizzled source slot

  // Q frags (B-operand 32x32x16): lane holds Q[q = w*32 + ln][d = dk*16 + h*8 ..+7]
  short8 qf[4];
  {
    const unsigned short* qrp = qp + (size_t)(w * 32 + ln) * HD;
#pragma unroll
    for (int dk = 0; dk < 4; ++dk)
      qf[dk] = *reinterpret_cast<const short8*>(qrp + dk * 16 + h * 8);
  }

  f32x16 acc0 = {}, acc1 = {};
  float lsum = 0.0f;   // per-lane (own k-half) partial

  auto KSTAGE = [&](int kv2, int bi2) {
    int rb = w * 8;                            // each wave stages 8 rows
    gl2lds16(kp + (size_t)(kv2 * 64 + rb + sr) * HD + sslot * 8, &Klds[bi2][rb * 64]);
  };
  auto VSTAGE = [&](int kv2, int bi2) {
    int rb = w * 8;
    gl2lds16(vtp + (size_t)(rb + sr) * TSEQ + kv2 * 64 + sslot * 8, &Vlds[bi2][rb * 64]);
  };

  if (tb < te) { KSTAGE(tb, 0); VSTAGE(tb, 0); }

  for (int kv = tb; kv < te; ++kv) {
    const int bi = (kv - tb) & 1;
    const char* Kb = reinterpret_cast<const char*>(&Klds[bi][0]);
    const char* Vb = reinterpret_cast<const char*>(&Vlds[bi][0]);
    __syncthreads();   // drains own DMA (tile kv landed); buf[bi^1] free
    if (kv + 1 < te) { KSTAGE(kv + 1, bi ^ 1); VSTAGE(kv + 1, bi ^ 1); }

    // ---- C-init: -16 (fixed shift) for interior tiles; bias array on last ----
    f32x16 st0, st1;
    if (kv == ntiles - 1) {
#pragma unroll
      for (int kt2 = 0; kt2 < 2; ++kt2) {
        f32x16& s = kt2 ? st1 : st0;
#pragma unroll
        for (int gg = 0; gg < 4; ++gg) {
          f32x4 m4 = *reinterpret_cast<const f32x4*>(mp + kv * 64 + kt2 * 32 + gg * 8 + 4 * h);
#pragma unroll
          for (int t = 0; t < 4; ++t) s[gg * 4 + t] = m4[t];
        }
      }
    } else {
#pragma unroll
      for (int r = 0; r < 16; ++r) { st0[r] = -16.0f; st1[r] = -16.0f; }
    }

    // ---- S^T = K Q^T + C. st rows k = kt2*32 + crow(r,h), col q = ln ----
    __builtin_amdgcn_s_setprio(1);
#pragma unroll
    for (int kt2 = 0; kt2 < 2; ++kt2) {
      f32x16& s = kt2 ? st1 : st0;
      int row = kt2 * 32 + ln;
#pragma unroll
      for (int dk = 0; dk < 4; ++dk) {
        int slot = (dk * 2 + h) ^ (row & 7);
        short8 kf = *reinterpret_cast<const short8*>(Kb + row * 128 + slot * 16);
        s = __builtin_amdgcn_mfma_f32_32x32x16_bf16(kf, qf[dk], s, 0, 0, 0);
      }
    }
    __builtin_amdgcn_s_setprio(0);

    // ---- P = exp2(S) directly (shift already in C-init); accumulate lsum ----
#pragma unroll
    for (int r = 0; r < 16; ++r) {
      st0[r] = __builtin_amdgcn_exp2f(st0[r]);
      st1[r] = __builtin_amdgcn_exp2f(st1[r]);
    }
    {
      f32x16 sv = st0 + st1;
      float s0 = (sv[0] + sv[1]) + (sv[2] + sv[3]);
      float s1 = (sv[4] + sv[5]) + (sv[6] + sv[7]);
      float s2 = (sv[8] + sv[9]) + (sv[10] + sv[11]);
      float s3 = (sv[12] + sv[13]) + (sv[14] + sv[15]);
      lsum += (s0 + s1) + (s2 + s3);
    }

    // ---- PV: build P A-frags in-register (cvt_pk + permlane), V from LDS ----
    __builtin_amdgcn_s_setprio(1);
#pragma unroll
    for (int ks = 0; ks < 4; ++ks) {
      const f32x16& p2 = (ks >> 1) ? st1 : st0;
      const int a = 8 * (ks & 1);
      unsigned X0 = pk2(p2[a + 0], p2[a + 1]);
      unsigned X1 = pk2(p2[a + 2], p2[a + 3]);
      unsigned Y0 = pk2(p2[a + 4], p2[a + 5]);
      unsigned Y1 = pk2(p2[a + 6], p2[a + 7]);
      pswap(X0, Y0);   // X0 -> words j0j1, Y0 -> words j4j5
      pswap(X1, Y1);   // X1 -> j2j3, Y1 -> j6j7
      union { unsigned u[4]; short8 s; } pf;
      pf.u[0] = X0; pf.u[1] = X1; pf.u[2] = Y0; pf.u[3] = Y1;
#pragma unroll
      for (int dc = 0; dc < 2; ++dc) {
        int row = dc * 32 + ln;
        int slot = (ks * 2 + h) ^ (row & 7);
        short8 vf = *reinterpret_cast<const short8*>(Vb + row * 128 + slot * 16);
        if (dc == 0)
          acc0 = __builtin_amdgcn_mfma_f32_32x32x16_bf16(pf.s, vf, acc0, 0, 0, 0);
        else
          acc1 = __builtin_amdgcn_mfma_f32_32x32x16_bf16(pf.s, vf, acc1, 0, 0, 0);
      }
    }
    __builtin_amdgcn_s_setprio(0);
  }

  // ---- epilogue: write UNNORMALIZED partials (combine_k divides) ----
  lsum += __shfl_xor(lsum, 32);
  const size_t rowbase = (size_t)(b * NH + head) * TSEQ + qb * 256 + w * 32;
  if (l < 32) pl[(size_t)split * BHT + rowbase + l] = lsum;
  unsigned short* pap = pa + (size_t)split * BHT * HD + rowbase * HD;
#pragma unroll
  for (int r = 0; r < 16; ++r) {
    int cr = (r & 3) + 8 * (r >> 2) + 4 * h;
    pap[cr * HD + ln] = f2bf(acc0[r]);
    pap[cr * HD + 32 + ln] = f2bf(acc1[r]);
  }
}

// ---------------- combine: c = (pa0 + pa1) / (l0 + l1), scatter to (B,T,H) ----
__global__ __launch_bounds__(256) void combine_k(
    const unsigned short* __restrict__ pa, const float* __restrict__ pl,
    unsigned short* __restrict__ c) {
  int gid = blockIdx.x * 256 + threadIdx.x;      // 0 .. BHT*HD/8-1
  int row = gid >> 3;                             // bh*TSEQ + t
  int d0 = (gid & 7) << 3;
  float inv = 1.0f / (pl[row] + pl[BHT + row]);
  const unsigned short* a0 = pa + (size_t)row * HD + d0;
  const unsigned short* a1 = a0 + (size_t)BHT * HD;
  short8 v0 = *reinterpret_cast<const short8*>(a0);
  short8 v1 = *reinterpret_cast<const short8*>(a1);
  union { unsigned short u[8]; short8 s; } o;
#pragma unroll
  for (int j = 0; j < 8; ++j)
    o.u[j] = f2bf((bf2f((unsigned short)v0[j]) + bf2f((unsigned short)v1[j])) * inv);
  int bh = row >> 11, t = row & (TSEQ - 1);
  int b = bh >> 4, head = bh & 15;
  *reinterpret_cast<short8*>(c + ((size_t)(b * TSEQ + t)) * HDIM + head * HD + d0) = o.s;
}

extern "C" void kernel_launch(void* const* d_in, const int* in_sizes, int n_in,
                              void* d_out, int out_size, void* d_ws, size_t ws_size,
                              hipStream_t stream) {
  const float* x   = (const float*)d_in[0];
  const int* mask  = (const int*)d_in[1];
  const float* lng = (const float*)d_in[2];
  const float* lnb = (const float*)d_in[3];
  const float* wq  = (const float*)d_in[4];
  const float* bq  = (const float*)d_in[5];
  const float* wk  = (const float*)d_in[6];
  const float* bk  = (const float*)d_in[7];
  const float* wv  = (const float*)d_in[8];
  const float* bv  = (const float*)d_in[9];
  const float* wo  = (const float*)d_in[10];
  const float* bo  = (const float*)d_in[11];
  float* out = (float*)d_out;
  char* ws = (char*)d_ws;

  unsigned short* h   = (unsigned short*)ws;                       // 16MB (B*T*H bf16)
  unsigned short* wbf = (unsigned short*)(ws + (16u << 20));       // 8MB (4 weights bf16)
  unsigned short* qs  = (unsigned short*)(ws + (24u << 20));       // 16MB
  unsigned short* ksb = (unsigned short*)(ws + (40u << 20));       // 16MB (compacted K)
  unsigned short* vt  = (unsigned short*)(ws + (56u << 20));       // 16MB (compacted V^T)
  float*          mzf = (float*)(ws + (72u << 20));                // 32KB pad bias
  int*            idx = (int*)(ws + (72u << 20) + (64u << 10));    // 32KB gather idx
  int*            met = (int*)(ws + (72u << 20) + (128u << 10));   // meta
  unsigned short* pa  = (unsigned short*)(ws + (76u << 20));       // 2x16MB partial O
  float*          pl  = (float*)(ws + (108u << 20));               // 2x512KB partial lsum
  unsigned short* c   = h;  // h dead after QKV GEMM

  prep_kernel<<<dim3(8192 + 4096 + BATCH), 256, 0, stream>>>(
      x, lng, lnb, h, wq, wk, wv, wo, wbf, mask, idx, mzf, met);
  gemm_k<0><<<dim3(1536), 512, 0, stream>>>(h, wbf, bq, bk, bv, qs, ksb, vt,
                                            nullptr, nullptr, idx, met);
  attn_kernel<<<dim3(1024), dim3(512), 0, stream>>>(qs, ksb, vt, mzf, met, pl, pa);
  combine_k<<<dim3(BHT * HD / 8 / 256), 256, 0, stream>>>(pa, pl, c);
  gemm_k<1><<<dim3(512), 512, 0, stream>>>(c, wbf + (size_t)3 * HDIM * HDIM, bo, nullptr, nullptr,
                                           nullptr, nullptr, nullptr, x, out, nullptr, nullptr);
}